// Round 1
// baseline (986.299 us; speedup 1.0000x reference)
//
#include <hip/hip_runtime.h>

// SpMM scatter-reduce: out[r] = sum_{e: rows[e]==r} vals[e] * embeds[cols[e]]
// N=100000 nodes, E=1600000 edges, D=48 fp32 features.

#define N_NODES 100000
#define N_EDGES 1600000
#define D_FEAT  48

// 12 float4-lanes per edge (12*4 = 48 features)
#define LANES_PER_EDGE 12

__global__ __launch_bounds__(256) void zero_out_kernel(float4* __restrict__ out, int n4) {
    int i = blockIdx.x * blockDim.x + threadIdx.x;
    if (i < n4) out[i] = make_float4(0.f, 0.f, 0.f, 0.f);
}

__global__ __launch_bounds__(256) void spmm_atomic_kernel(
    const int* __restrict__ rows,
    const int* __restrict__ cols,
    const float* __restrict__ vals,
    const float* __restrict__ embeds,
    float* __restrict__ out)
{
    long long tid = (long long)blockIdx.x * blockDim.x + threadIdx.x;
    const long long total = (long long)N_EDGES * LANES_PER_EDGE;
    if (tid >= total) return;

    int e = (int)(tid / LANES_PER_EDGE);
    int q = (int)(tid % LANES_PER_EDGE);   // which float4 chunk of the 48 features

    int   r = rows[e];
    int   c = cols[e];
    float v = vals[e];

    const float4 emb = *(const float4*)(embeds + (long long)c * D_FEAT + q * 4);
    float* o = out + (long long)r * D_FEAT + q * 4;

    atomicAdd(o + 0, v * emb.x);
    atomicAdd(o + 1, v * emb.y);
    atomicAdd(o + 2, v * emb.z);
    atomicAdd(o + 3, v * emb.w);
}

extern "C" void kernel_launch(void* const* d_in, const int* in_sizes, int n_in,
                              void* d_out, int out_size, void* d_ws, size_t ws_size,
                              hipStream_t stream) {
    const int*   rows   = (const int*)d_in[0];
    const int*   cols   = (const int*)d_in[1];
    const float* vals   = (const float*)d_in[2];
    const float* embeds = (const float*)d_in[3];
    float*       out    = (float*)d_out;

    // 1) zero the output (atomics accumulate; harness does not re-poison)
    int n4 = out_size / 4;  // out_size = 100000*48, divisible by 4
    int zb = (n4 + 255) / 256;
    zero_out_kernel<<<zb, 256, 0, stream>>>((float4*)out, n4);

    // 2) edge-parallel atomic scatter
    long long total = (long long)N_EDGES * LANES_PER_EDGE;
    int blocks = (int)((total + 255) / 256);
    spmm_atomic_kernel<<<blocks, 256, 0, stream>>>(rows, cols, vals, embeds, out);
}

// Round 2
// 575.890 us; speedup vs baseline: 1.7127x; 1.7127x over previous
//
#include <hip/hip_runtime.h>

// SpMM scatter-reduce: out[r] = sum_{e: rows[e]==r} vals[e] * embeds[cols[e]]
// Strategy: device-side CSR build (hist + scan + scatter into d_ws), then
// atomic-free row-parallel SpMM: one wave per row, lane = feature dim.

#define N_NODES 100000
#define N_EDGES 1600000
#define D_FEAT  48

__global__ __launch_bounds__(256) void zero_counts_kernel(unsigned int* __restrict__ counts, int n) {
    int i = blockIdx.x * 256 + threadIdx.x;
    if (i < n) counts[i] = 0u;
}

__global__ __launch_bounds__(256) void hist_kernel(const int* __restrict__ rows,
                                                   unsigned int* __restrict__ counts) {
    int e = blockIdx.x * 256 + threadIdx.x;
    if (e < N_EDGES) atomicAdd(&counts[rows[e]], 1u);
}

// Single-workgroup exclusive scan over counts[0..N): counts becomes offsets
// (in place), cursor gets a copy. counts[N] = E.
__global__ __launch_bounds__(1024) void scan_kernel(unsigned int* __restrict__ counts,
                                                    unsigned int* __restrict__ cursor) {
    __shared__ unsigned int s[1024];
    const int t = threadIdx.x;
    const int chunk = (N_NODES + 1023) / 1024;  // 98
    const int lo = t * chunk;
    const int hi = (lo + chunk < N_NODES) ? lo + chunk : N_NODES;

    unsigned int sum = 0;
    for (int i = lo; i < hi; ++i) sum += counts[i];
    s[t] = sum;
    __syncthreads();
    for (int off = 1; off < 1024; off <<= 1) {
        unsigned int v = 0;
        if (t >= off) v = s[t - off];
        __syncthreads();
        if (t >= off) s[t] += v;
        __syncthreads();
    }
    unsigned int running = (t == 0) ? 0u : s[t - 1];
    for (int i = lo; i < hi; ++i) {
        unsigned int c = counts[i];
        counts[i] = running;
        cursor[i] = running;
        running += c;
    }
    if (t == 0) counts[N_NODES] = N_EDGES;
}

__global__ __launch_bounds__(256) void scatter_kernel(const int* __restrict__ rows,
                                                      const int* __restrict__ cols,
                                                      const float* __restrict__ vals,
                                                      unsigned int* __restrict__ cursor,
                                                      int2* __restrict__ colval) {
    int e = blockIdx.x * 256 + threadIdx.x;
    if (e < N_EDGES) {
        int r = rows[e];
        unsigned int pos = atomicAdd(&cursor[r], 1u);
        colval[pos] = make_int2(cols[e], __float_as_int(vals[e]));
    }
}

// One 64-lane wave per row; lanes 0..47 each own one feature dim.
__global__ __launch_bounds__(256) void spmm_kernel(const unsigned int* __restrict__ offsets,
                                                   const int2* __restrict__ colval,
                                                   const float* __restrict__ embeds,
                                                   float* __restrict__ out) {
    int row  = blockIdx.x * 4 + (threadIdx.x >> 6);
    int lane = threadIdx.x & 63;
    if (row >= N_NODES) return;

    unsigned int j   = offsets[row];
    unsigned int end = offsets[row + 1];
    float acc = 0.f;
    for (; j < end; ++j) {
        int2 cv = colval[j];  // broadcast load (same addr across wave)
        if (lane < D_FEAT)
            acc = fmaf(__int_as_float(cv.y), embeds[(long long)cv.x * D_FEAT + lane], acc);
    }
    if (lane < D_FEAT) out[(long long)row * D_FEAT + lane] = acc;
}

extern "C" void kernel_launch(void* const* d_in, const int* in_sizes, int n_in,
                              void* d_out, int out_size, void* d_ws, size_t ws_size,
                              hipStream_t stream) {
    const int*   rows   = (const int*)d_in[0];
    const int*   cols   = (const int*)d_in[1];
    const float* vals   = (const float*)d_in[2];
    const float* embeds = (const float*)d_in[3];
    float*       out    = (float*)d_out;

    // workspace layout
    unsigned int* counts = (unsigned int*)d_ws;          // N+1 (becomes offsets)
    unsigned int* cursor = counts + (N_NODES + 1);       // N
    size_t cv_off = (((size_t)(2 * N_NODES + 1) * 4) + 7) & ~(size_t)7;
    int2* colval = (int2*)((char*)d_ws + cv_off);        // E * 8 bytes

    const int EB = (N_EDGES + 255) / 256;  // 6250

    zero_counts_kernel<<<(N_NODES + 256) / 256, 256, 0, stream>>>(counts, N_NODES + 1);
    hist_kernel<<<EB, 256, 0, stream>>>(rows, counts);
    scan_kernel<<<1, 1024, 0, stream>>>(counts, cursor);
    scatter_kernel<<<EB, 256, 0, stream>>>(rows, cols, vals, cursor, colval);
    spmm_kernel<<<(N_NODES + 3) / 4, 256, 0, stream>>>(counts, colval, embeds, out);
}

// Round 3
// 285.204 us; speedup vs baseline: 3.4582x; 2.0192x over previous
//
#include <hip/hip_runtime.h>

// SpMM scatter-reduce: out[r] = sum_{e: rows[e]==r} vals[e] * embeds[cols[e]]
// CSR build (hist + 3-phase device-wide scan + scatter into d_ws), then
// atomic-free row-parallel SpMM: one wave per row, lane = feature dim,
// edge loop unrolled x4 for gather ILP.

#define N_NODES 100000
#define N_EDGES 1600000
#define D_FEAT  48

#define SCAN_CHUNK 1024                                   // items per scan block
#define NB_SCAN ((N_NODES + SCAN_CHUNK - 1) / SCAN_CHUNK) // 98

__global__ __launch_bounds__(256) void zero_counts_kernel(unsigned int* __restrict__ counts, int n) {
    int i = blockIdx.x * 256 + threadIdx.x;
    if (i < n) counts[i] = 0u;
}

__global__ __launch_bounds__(256) void hist_kernel(const int* __restrict__ rows,
                                                   unsigned int* __restrict__ counts) {
    int e = blockIdx.x * 256 + threadIdx.x;
    if (e < N_EDGES) atomicAdd(&counts[rows[e]], 1u);
}

// Phase 1: per-block sums of counts chunks.
__global__ __launch_bounds__(256) void scan_phase1(const unsigned int* __restrict__ counts,
                                                   unsigned int* __restrict__ bsum) {
    __shared__ unsigned int s[256];
    const int b = blockIdx.x, t = threadIdx.x;
    const int base = b * SCAN_CHUNK + t * 4;
    unsigned int sum = 0;
#pragma unroll
    for (int k = 0; k < 4; ++k) {
        int i = base + k;
        if (i < N_NODES) sum += counts[i];
    }
    s[t] = sum;
    __syncthreads();
    for (int off = 128; off > 0; off >>= 1) {
        if (t < off) s[t] += s[t + off];
        __syncthreads();
    }
    if (t == 0) bsum[b] = s[0];
}

// Phase 2: exclusive scan of the 98 block sums (single tiny block).
__global__ __launch_bounds__(128) void scan_phase2(unsigned int* __restrict__ bsum) {
    __shared__ unsigned int s[128];
    const int t = threadIdx.x;
    unsigned int v = (t < NB_SCAN) ? bsum[t] : 0u;
    s[t] = v;
    __syncthreads();
    for (int off = 1; off < 128; off <<= 1) {
        unsigned int u = (t >= off) ? s[t - off] : 0u;
        __syncthreads();
        s[t] += u;
        __syncthreads();
    }
    if (t < NB_SCAN) bsum[t] = (t == 0) ? 0u : s[t - 1];
}

// Phase 3: per-block exclusive rescan + block offset; counts becomes offsets
// in place, cursor gets a copy; counts[N] = E.
__global__ __launch_bounds__(256) void scan_phase3(unsigned int* __restrict__ counts,
                                                   const unsigned int* __restrict__ bsum,
                                                   unsigned int* __restrict__ cursor) {
    __shared__ unsigned int s[256];
    const int b = blockIdx.x, t = threadIdx.x;
    const int base = b * SCAN_CHUNK + t * 4;
    unsigned int c[4];
    unsigned int sum = 0;
#pragma unroll
    for (int k = 0; k < 4; ++k) {
        int i = base + k;
        c[k] = (i < N_NODES) ? counts[i] : 0u;
        sum += c[k];
    }
    s[t] = sum;
    __syncthreads();
    for (int off = 1; off < 256; off <<= 1) {
        unsigned int u = (t >= off) ? s[t - off] : 0u;
        __syncthreads();
        s[t] += u;
        __syncthreads();
    }
    unsigned int prefix = bsum[b] + ((t == 0) ? 0u : s[t - 1]);
#pragma unroll
    for (int k = 0; k < 4; ++k) {
        int i = base + k;
        if (i < N_NODES) {
            counts[i] = prefix;
            cursor[i] = prefix;
            prefix += c[k];
        }
    }
    if (b == 0 && t == 0) counts[N_NODES] = N_EDGES;
}

__global__ __launch_bounds__(256) void scatter_kernel(const int* __restrict__ rows,
                                                      const int* __restrict__ cols,
                                                      const float* __restrict__ vals,
                                                      unsigned int* __restrict__ cursor,
                                                      int2* __restrict__ colval) {
    int e = blockIdx.x * 256 + threadIdx.x;
    if (e < N_EDGES) {
        int r = rows[e];
        unsigned int pos = atomicAdd(&cursor[r], 1u);
        colval[pos] = make_int2(cols[e], __float_as_int(vals[e]));
    }
}

// One 64-lane wave per row; lanes 0..47 each own one feature dim.
// Edge loop unrolled x4: 4 independent 192B gathers in flight.
__global__ __launch_bounds__(256) void spmm_kernel(const unsigned int* __restrict__ offsets,
                                                   const int2* __restrict__ colval,
                                                   const float* __restrict__ embeds,
                                                   float* __restrict__ out) {
    int row  = blockIdx.x * 4 + (threadIdx.x >> 6);
    int lane = threadIdx.x & 63;
    if (row >= N_NODES) return;

    unsigned int j   = offsets[row];
    unsigned int end = offsets[row + 1];
    float acc = 0.f;

    for (; j + 4 <= end; j += 4) {
        int2 cv0 = colval[j + 0];
        int2 cv1 = colval[j + 1];
        int2 cv2 = colval[j + 2];
        int2 cv3 = colval[j + 3];
        if (lane < D_FEAT) {
            float e0 = embeds[(long long)cv0.x * D_FEAT + lane];
            float e1 = embeds[(long long)cv1.x * D_FEAT + lane];
            float e2 = embeds[(long long)cv2.x * D_FEAT + lane];
            float e3 = embeds[(long long)cv3.x * D_FEAT + lane];
            acc = fmaf(__int_as_float(cv0.y), e0, acc);
            acc = fmaf(__int_as_float(cv1.y), e1, acc);
            acc = fmaf(__int_as_float(cv2.y), e2, acc);
            acc = fmaf(__int_as_float(cv3.y), e3, acc);
        }
    }
    for (; j < end; ++j) {
        int2 cv = colval[j];
        if (lane < D_FEAT)
            acc = fmaf(__int_as_float(cv.y), embeds[(long long)cv.x * D_FEAT + lane], acc);
    }
    if (lane < D_FEAT) out[(long long)row * D_FEAT + lane] = acc;
}

extern "C" void kernel_launch(void* const* d_in, const int* in_sizes, int n_in,
                              void* d_out, int out_size, void* d_ws, size_t ws_size,
                              hipStream_t stream) {
    const int*   rows   = (const int*)d_in[0];
    const int*   cols   = (const int*)d_in[1];
    const float* vals   = (const float*)d_in[2];
    const float* embeds = (const float*)d_in[3];
    float*       out    = (float*)d_out;

    // workspace layout
    unsigned int* counts = (unsigned int*)d_ws;          // N+1 (becomes offsets)
    unsigned int* cursor = counts + (N_NODES + 1);       // N
    unsigned int* bsum   = cursor + N_NODES;             // NB_SCAN
    size_t cv_off = (((size_t)(2 * N_NODES + 1 + NB_SCAN) * 4) + 7) & ~(size_t)7;
    int2* colval = (int2*)((char*)d_ws + cv_off);        // E * 8 bytes

    const int EB = (N_EDGES + 255) / 256;  // 6250

    zero_counts_kernel<<<(N_NODES + 256) / 256, 256, 0, stream>>>(counts, N_NODES + 1);
    hist_kernel<<<EB, 256, 0, stream>>>(rows, counts);
    scan_phase1<<<NB_SCAN, 256, 0, stream>>>(counts, bsum);
    scan_phase2<<<1, 128, 0, stream>>>(bsum);
    scan_phase3<<<NB_SCAN, 256, 0, stream>>>(counts, bsum, cursor);
    scatter_kernel<<<EB, 256, 0, stream>>>(rows, cols, vals, cursor, colval);
    spmm_kernel<<<(N_NODES + 3) / 4, 256, 0, stream>>>(counts, colval, embeds, out);
}